// Round 1
// baseline (1320.745 us; speedup 1.0000x reference)
//
#include <hip/hip_runtime.h>
#include <hip/hip_bf16.h>
#include <stdint.h>

#define D_MODEL 1024
#define D_FF    4096
#define NEXP    8
#define NTOK    8192
#define NSLOT   16384

typedef __bf16 bf16x8 __attribute__((ext_vector_type(8)));
typedef float  f32x4  __attribute__((ext_vector_type(4)));
typedef unsigned short us8 __attribute__((ext_vector_type(8)));
typedef unsigned short us4 __attribute__((ext_vector_type(4)));

// ---- ws layout (bytes) ----
#define OFF_XB   0ull                      // 8192*1024*2        = 16,777,216
#define OFF_WGT  16777216ull               // 8*4096*1024*2      = 67,108,864
#define OFF_WUT  83886080ull               // 67,108,864
#define OFF_WDT  150994944ull              // 8*1024*4096*2      = 67,108,864
#define OFF_H    218103808ull              // 16384*4096*2       = 134,217,728
#define OFF_TOKE 352321536ull              // 16384 * int
#define OFF_TOKW 352387072ull              // 16384 * float
#define OFF_ROWT 352452608ull              // 16384 * int
#define OFF_WGTL 352518144ull              // 16384 * float
#define OFF_CNT  352583680ull              // 8 * int
#define OFF_OFFS 352583744ull              // 9 * int
#define OFF_FILL 352583808ull              // 8 * int

__device__ __forceinline__ unsigned short f2b(float f) {
  union { float f; unsigned int u; } v; v.f = f;
  unsigned int r = (v.u + 0x7FFFu + ((v.u >> 16) & 1u)) >> 16;  // RNE
  return (unsigned short)r;
}

__device__ __forceinline__ f32x4 MFMA(bf16x8 a, bf16x8 b, f32x4 c) {
  return __builtin_amdgcn_mfma_f32_16x16x32_bf16(a, b, c, 0, 0, 0);
}

__device__ __forceinline__ void GLL16(const void* g, void* l) {
  __builtin_amdgcn_global_load_lds(
      (__attribute__((address_space(1))) void*)g,
      (__attribute__((address_space(3))) void*)l, 16, 0, 0);
}

// ---------------- x -> bf16 ----------------
__global__ __launch_bounds__(256) void k_cvt_x(const float* __restrict__ x,
                                               unsigned short* __restrict__ xb) {
  size_t i = ((size_t)blockIdx.x * 256 + threadIdx.x) * 8;
  float4 a = *(const float4*)(x + i);
  float4 b = *(const float4*)(x + i + 4);
  us8 o;
  o[0]=f2b(a.x); o[1]=f2b(a.y); o[2]=f2b(a.z); o[3]=f2b(a.w);
  o[4]=f2b(b.x); o[5]=f2b(b.y); o[6]=f2b(b.z); o[7]=f2b(b.w);
  *(us8*)(xb + i) = o;
}

// ------------- transpose+convert: in [E][R][C] f32 -> out [E][C][R] bf16 -------------
__global__ __launch_bounds__(256) void k_tc(const float* __restrict__ in,
                                            unsigned short* __restrict__ out,
                                            int R, int C) {
  __shared__ float t[64][65];
  int e = blockIdx.z;
  int r0 = blockIdx.y * 64, c0 = blockIdx.x * 64;
  const float* src = in + (size_t)e * R * C;
  unsigned short* dst = out + (size_t)e * R * C;
  int tid = threadIdx.x;
  int lr = tid >> 4;          // 0..15
  int lc = (tid & 15) * 4;    // 0..60
#pragma unroll
  for (int i = 0; i < 4; ++i) {
    float4 v = *(const float4*)(src + (size_t)(r0 + lr + 16 * i) * C + c0 + lc);
    t[lr + 16 * i][lc + 0] = v.x;
    t[lr + 16 * i][lc + 1] = v.y;
    t[lr + 16 * i][lc + 2] = v.z;
    t[lr + 16 * i][lc + 3] = v.w;
  }
  __syncthreads();
#pragma unroll
  for (int i = 0; i < 4; ++i) {
    int c = lr + 16 * i;
    us4 o;
    o[0] = f2b(t[lc + 0][c]);
    o[1] = f2b(t[lc + 1][c]);
    o[2] = f2b(t[lc + 2][c]);
    o[3] = f2b(t[lc + 3][c]);
    *(us4*)(dst + (size_t)(c0 + c) * R + r0 + lc) = o;
  }
}

// ---------------- router: fp32 logits, softmax-top2 ----------------
__global__ __launch_bounds__(256) void k_router(const float* __restrict__ x,
                                                const float* __restrict__ rw,
                                                int* __restrict__ tok_e,
                                                float* __restrict__ tok_w,
                                                int* __restrict__ counts) {
  int w = threadIdx.x >> 6, l = threadIdx.x & 63;
  int t = blockIdx.x * 4 + w;
  const float* xr = x + (size_t)t * D_MODEL + l * 16;
  float4 xa = *(const float4*)(xr);
  float4 xb4 = *(const float4*)(xr + 4);
  float4 xc = *(const float4*)(xr + 8);
  float4 xd = *(const float4*)(xr + 12);
  float lg[NEXP];
#pragma unroll
  for (int e = 0; e < NEXP; ++e) {
    const float* wr = rw + e * D_MODEL + l * 16;
    float4 wa = *(const float4*)(wr);
    float4 wb = *(const float4*)(wr + 4);
    float4 wc = *(const float4*)(wr + 8);
    float4 wd4 = *(const float4*)(wr + 12);
    float s = xa.x*wa.x + xa.y*wa.y + xa.z*wa.z + xa.w*wa.w
            + xb4.x*wb.x + xb4.y*wb.y + xb4.z*wb.z + xb4.w*wb.w
            + xc.x*wc.x + xc.y*wc.y + xc.z*wc.z + xc.w*wc.w
            + xd.x*wd4.x + xd.y*wd4.y + xd.z*wd4.z + xd.w*wd4.w;
#pragma unroll
    for (int o = 32; o; o >>= 1) s += __shfl_xor(s, o, 64);
    lg[e] = s;
  }
  if (l == 0) {
    int e1 = 0; float l1 = lg[0];
#pragma unroll
    for (int e = 1; e < NEXP; ++e) if (lg[e] > l1) { l1 = lg[e]; e1 = e; }
    int e2 = -1; float l2 = -3.4e38f;
#pragma unroll
    for (int e = 0; e < NEXP; ++e) if (e != e1 && lg[e] > l2) { l2 = lg[e]; e2 = e; }
    float w1 = 1.f / (1.f + expf(l2 - l1));
    tok_e[2 * t] = e1; tok_e[2 * t + 1] = e2;
    tok_w[2 * t] = w1; tok_w[2 * t + 1] = 1.f - w1;
    atomicAdd(&counts[e1], 1);
    atomicAdd(&counts[e2], 1);
  }
}

__global__ void k_scan(const int* __restrict__ counts, int* __restrict__ offs) {
  if (threadIdx.x == 0) {
    int s = 0;
#pragma unroll
    for (int e = 0; e < NEXP; ++e) { offs[e] = s; s += counts[e]; }
    offs[NEXP] = s;
  }
}

__global__ __launch_bounds__(256) void k_scatter(const int* __restrict__ tok_e,
                                                 const float* __restrict__ tok_w,
                                                 const int* __restrict__ offs,
                                                 int* __restrict__ fill,
                                                 int* __restrict__ rowtok,
                                                 float* __restrict__ wgtl) {
  int t = blockIdx.x * 256 + threadIdx.x;
#pragma unroll
  for (int k = 0; k < 2; ++k) {
    int e = tok_e[2 * t + k];
    int p = atomicAdd(&fill[e], 1);
    int s = offs[e] + p;
    rowtok[s] = t;
    wgtl[s] = tok_w[2 * t + k];
  }
}

// ---------------- pass A: h = silu(x@wg) * (x@wu), per expert, compacted rows ----------------
__global__ __launch_bounds__(256, 2) void k_gateup(
    const unsigned short* __restrict__ xb,
    const unsigned short* __restrict__ wgT,
    const unsigned short* __restrict__ wuT,
    const int* __restrict__ rowtok,
    const int* __restrict__ offs,
    unsigned short* __restrict__ h) {
  int e = blockIdx.z;
  int eoff = offs[e];
  int cnt = offs[e + 1] - eoff;
  int m0 = blockIdx.y * 128;
  if (m0 >= cnt) return;
  int f0 = blockIdx.x * 128;

  __shared__ __align__(16) unsigned short lA[8192];
  __shared__ __align__(16) unsigned short lG[8192];
  __shared__ __align__(16) unsigned short lU[8192];

  int tid = threadIdx.x;
  int l = tid & 63, w = tid >> 6;
  int wm = w >> 1, wn = w & 1;
  int lrow = l & 15, lk = (l >> 4) * 8;
  int scol = (tid & 7) * 8;

  const unsigned short* wgp = wgT + (size_t)e * D_FF * D_MODEL;
  const unsigned short* wup = wuT + (size_t)e * D_FF * D_MODEL;

  const unsigned short* aptr[4];
  const unsigned short* gptr[4];
  const unsigned short* uptr[4];
#pragma unroll
  for (int r = 0; r < 4; ++r) {
    int mrow = m0 + (tid >> 3) + 32 * r;
    int srow = rowtok[eoff + (mrow < cnt ? mrow : cnt - 1)];
    aptr[r] = xb + (size_t)srow * D_MODEL + scol;
    int frow = f0 + (tid >> 3) + 32 * r;
    gptr[r] = wgp + (size_t)frow * D_MODEL + scol;
    uptr[r] = wup + (size_t)frow * D_MODEL + scol;
  }

  f32x4 zero = {0.f, 0.f, 0.f, 0.f};
  f32x4 ag[4][4], au[4][4];
#pragma unroll
  for (int i = 0; i < 4; ++i)
#pragma unroll
    for (int j = 0; j < 4; ++j) { ag[i][j] = zero; au[i][j] = zero; }

  unsigned short* lAw = lA + w * 512;
  unsigned short* lGw = lG + w * 512;
  unsigned short* lUw = lU + w * 512;

  for (int ks = 0; ks < 16; ++ks) {
    int k0 = ks * 64;
    __syncthreads();
#pragma unroll
    for (int r = 0; r < 4; ++r) {
      GLL16(aptr[r] + k0, lAw + r * 2048);
      GLL16(gptr[r] + k0, lGw + r * 2048);
      GLL16(uptr[r] + k0, lUw + r * 2048);
    }
    __syncthreads();
#pragma unroll
    for (int kk = 0; kk < 2; ++kk) {
      bf16x8 av[4], gv[4], uv[4];
#pragma unroll
      for (int i = 0; i < 4; ++i) {
        av[i] = *(const bf16x8*)&lA[(wm * 64 + i * 16 + lrow) * 64 + kk * 32 + lk];
        gv[i] = *(const bf16x8*)&lG[(wn * 64 + i * 16 + lrow) * 64 + kk * 32 + lk];
        uv[i] = *(const bf16x8*)&lU[(wn * 64 + i * 16 + lrow) * 64 + kk * 32 + lk];
      }
#pragma unroll
      for (int mi = 0; mi < 4; ++mi)
#pragma unroll
        for (int ni = 0; ni < 4; ++ni) {
          ag[mi][ni] = MFMA(av[mi], gv[ni], ag[mi][ni]);
          au[mi][ni] = MFMA(av[mi], uv[ni], au[mi][ni]);
        }
    }
  }

  // epilogue: h = silu(g)*u  (C/D layout: col=lane&15, row=(lane>>4)*4+reg)
#pragma unroll
  for (int mi = 0; mi < 4; ++mi) {
#pragma unroll
    for (int j = 0; j < 4; ++j) {
      int row = wm * 64 + mi * 16 + (l >> 4) * 4 + j;
      if (m0 + row < cnt) {
        size_t hb = (size_t)(eoff + m0 + row) * D_FF + f0;
#pragma unroll
        for (int ni = 0; ni < 4; ++ni) {
          int col = wn * 64 + ni * 16 + (l & 15);
          float g = ag[mi][ni][j];
          float u = au[mi][ni][j];
          float s = g / (1.f + __expf(-g)) * u;
          h[hb + col] = f2b(s);
        }
      }
    }
  }
}

// ---------------- pass B: out += w * (h @ wd) ----------------
__global__ __launch_bounds__(256, 2) void k_down(
    const unsigned short* __restrict__ h,
    const unsigned short* __restrict__ wdT,
    const int* __restrict__ rowtok,
    const float* __restrict__ wgtl,
    const int* __restrict__ offs,
    float* __restrict__ out) {
  int e = blockIdx.z;
  int eoff = offs[e];
  int cnt = offs[e + 1] - eoff;
  int m0 = blockIdx.y * 128;
  if (m0 >= cnt) return;
  int d0 = blockIdx.x * 128;

  __shared__ __align__(16) unsigned short lA[8192];
  __shared__ __align__(16) unsigned short lB[8192];

  int tid = threadIdx.x;
  int l = tid & 63, w = tid >> 6;
  int wm = w >> 1, wn = w & 1;
  int lrow = l & 15, lk = (l >> 4) * 8;
  int scol = (tid & 7) * 8;

  const unsigned short* wdp = wdT + (size_t)e * D_MODEL * D_FF;
  const unsigned short* aptr[4];
  const unsigned short* bptr[4];
#pragma unroll
  for (int r = 0; r < 4; ++r) {
    int mrow = m0 + (tid >> 3) + 32 * r;
    aptr[r] = h + (size_t)(eoff + (mrow < cnt ? mrow : cnt - 1)) * D_FF + scol;
    bptr[r] = wdp + (size_t)(d0 + (tid >> 3) + 32 * r) * D_FF + scol;
  }

  f32x4 zero = {0.f, 0.f, 0.f, 0.f};
  f32x4 ac[4][4];
#pragma unroll
  for (int i = 0; i < 4; ++i)
#pragma unroll
    for (int j = 0; j < 4; ++j) ac[i][j] = zero;

  unsigned short* lAw = lA + w * 512;
  unsigned short* lBw = lB + w * 512;

  for (int ks = 0; ks < 64; ++ks) {
    int k0 = ks * 64;
    __syncthreads();
#pragma unroll
    for (int r = 0; r < 4; ++r) {
      GLL16(aptr[r] + k0, lAw + r * 2048);
      GLL16(bptr[r] + k0, lBw + r * 2048);
    }
    __syncthreads();
#pragma unroll
    for (int kk = 0; kk < 2; ++kk) {
      bf16x8 av[4], bv[4];
#pragma unroll
      for (int i = 0; i < 4; ++i) {
        av[i] = *(const bf16x8*)&lA[(wm * 64 + i * 16 + lrow) * 64 + kk * 32 + lk];
        bv[i] = *(const bf16x8*)&lB[(wn * 64 + i * 16 + lrow) * 64 + kk * 32 + lk];
      }
#pragma unroll
      for (int mi = 0; mi < 4; ++mi)
#pragma unroll
        for (int ni = 0; ni < 4; ++ni)
          ac[mi][ni] = MFMA(av[mi], bv[ni], ac[mi][ni]);
    }
  }

#pragma unroll
  for (int mi = 0; mi < 4; ++mi) {
#pragma unroll
    for (int j = 0; j < 4; ++j) {
      int row = wm * 64 + mi * 16 + (l >> 4) * 4 + j;
      int grow = m0 + row;
      if (grow < cnt) {
        float wv = wgtl[eoff + grow];
        int tok = rowtok[eoff + grow];
        float* ob = out + (size_t)tok * D_MODEL + d0;
#pragma unroll
        for (int ni = 0; ni < 4; ++ni) {
          int col = wn * 64 + ni * 16 + (l & 15);
          atomicAdd(ob + col, ac[mi][ni][j] * wv);
        }
      }
    }
  }
}

extern "C" void kernel_launch(void* const* d_in, const int* in_sizes, int n_in,
                              void* d_out, int out_size, void* d_ws, size_t ws_size,
                              hipStream_t stream) {
  const float* x  = (const float*)d_in[0];
  const float* rw = (const float*)d_in[1];
  const float* wg = (const float*)d_in[2];
  const float* wu = (const float*)d_in[3];
  const float* wd = (const float*)d_in[4];
  float* out = (float*)d_out;
  char* ws = (char*)d_ws;

  unsigned short* xb  = (unsigned short*)(ws + OFF_XB);
  unsigned short* wgT = (unsigned short*)(ws + OFF_WGT);
  unsigned short* wuT = (unsigned short*)(ws + OFF_WUT);
  unsigned short* wdT = (unsigned short*)(ws + OFF_WDT);
  unsigned short* hb  = (unsigned short*)(ws + OFF_H);
  int*   tok_e  = (int*)(ws + OFF_TOKE);
  float* tok_w  = (float*)(ws + OFF_TOKW);
  int*   rowtok = (int*)(ws + OFF_ROWT);
  float* wgtl   = (float*)(ws + OFF_WGTL);
  int*   counts = (int*)(ws + OFF_CNT);
  int*   offs   = (int*)(ws + OFF_OFFS);
  int*   fill   = (int*)(ws + OFF_FILL);

  hipMemsetAsync(out, 0, (size_t)NTOK * D_MODEL * 4, stream);
  hipMemsetAsync(ws + OFF_CNT, 0, 192, stream);

  k_cvt_x<<<4096, 256, 0, stream>>>(x, xb);
  k_tc<<<dim3(64, 16, 8), 256, 0, stream>>>(wg, wgT, D_MODEL, D_FF);  // [D][F] -> [F][D]
  k_tc<<<dim3(64, 16, 8), 256, 0, stream>>>(wu, wuT, D_MODEL, D_FF);
  k_tc<<<dim3(16, 64, 8), 256, 0, stream>>>(wd, wdT, D_FF, D_MODEL);  // [F][D] -> [D][F]

  k_router<<<NTOK / 4, 256, 0, stream>>>(x, rw, tok_e, tok_w, counts);
  k_scan<<<1, 64, 0, stream>>>(counts, offs);
  k_scatter<<<NTOK / 256, 256, 0, stream>>>(tok_e, tok_w, offs, fill, rowtok, wgtl);

  k_gateup<<<dim3(32, 64, 8), 256, 0, stream>>>(xb, wgT, wuT, rowtok, offs, hb);
  k_down<<<dim3(8, 64, 8), 256, 0, stream>>>(hb, wdT, rowtok, wgtl, offs, out);
}